// Round 16
// baseline (31.484 us; speedup 1.0000x reference)
//
#include <hip/hip_runtime.h>
#include <math.h>

namespace {

constexpr int kD = 1024;
constexpr int kL = 1024;
constexpr int kN = 16;
constexpr int kE = 4;     // l-steps per thread
constexpr int kJ = 8;     // n-states per thread (one nh half)
constexpr int kT = 512;   // threads per block; block = one (b,d)
constexpr int kC = 256;   // l-chunks per (b,d)
constexpr int kCP = kC + 1;

// wave-uniform float -> SGPR
__device__ __forceinline__ float rfl(float x) {
    return __uint_as_float(__builtin_amdgcn_readfirstlane(__float_as_uint(x)));
}

__global__ __launch_bounds__(kT)
void selscan(const float* __restrict__ u,
             const float* __restrict__ delta,
             const float* __restrict__ A,
             const float* __restrict__ Bm,
             const float* __restrict__ Cm,
             const float* __restrict__ Dv,
             const float* __restrict__ z,
             float* __restrict__ out)
{
    __shared__ float2 sax[kN][kCP];  // [n][chunk] (a,x); .x -> carry after scan
    __shared__ float2 sw[8][kN];     // per-wave 32-chunk totals
    __shared__ float2 syr[2][kC];    // cross-half y exchange (4 KB)

    const int bd   = blockIdx.x;
    const int b    = bd >> 10;          // kD = 1024
    const int d    = bd & (kD - 1);
    const int t    = threadIdx.x;
    const int lane = t & 63;
    const int wave = t >> 6;
    const int nh   = wave >> 2;         // waves 0-3: n 0-7; waves 4-7: n 8-15
    const int n0   = nh << 3;
    const int chunk = ((wave & 3) << 6) | lane;   // 0..255
    const int l0   = chunk << 2;
    const size_t base = (size_t)bd * kL;

    const float LOG2E = 1.4426950408889634f;
    const float LN2   = 0.6931471805599453f;

    // ---- early z preload (epilogue-only; latency hides under phase 1) ----
    float2 zv2 = *(const float2*)(z + base + l0 + 2 * nh);

    // ---- softplus: dt2 = dt*log2e, dtu = dt*u; keep epilogue-u in regs ----
    float dt2[kE], dtu[kE];
    float ue0, ue1;
    {
        float4 dv = *(const float4*)(delta + base + l0);
        float4 uv = *(const float4*)(u + base + l0);
        float dd[4] = {dv.x, dv.y, dv.z, dv.w};
        float uu[4] = {uv.x, uv.y, uv.z, uv.w};
        #pragma unroll
        for (int s = 0; s < kE; ++s) {
            float x = dd[s];
            float e = __builtin_amdgcn_exp2f(-fabsf(x) * LOG2E);
            float sp = fmaxf(x, 0.f) + __builtin_amdgcn_logf(1.f + e) * LN2;
            dt2[s] = sp * LOG2E;
            dtu[s] = sp * uu[s];
        }
        // this thread's epilogue elements: l0 + 2*nh + {0,1}
        ue0 = nh ? uu[2] : uu[0];
        ue1 = nh ? uu[3] : uu[1];
    }

    // ---- A row for this wave's n-half -> SGPRs (wave-uniform) ----
    float aj[kJ];
    {
        const float* Ap = A + d * kN + n0;
        #pragma unroll
        for (int j = 0; j < kJ; ++j) aj[j] = rfl(Ap[j]);
    }

    // ---- Phase 1: local 4-step scan; y_local; Q = P*C (R12 load scheme) ----
    float Q[kJ][kE];
    float y[kE] = {0.f, 0.f, 0.f, 0.f};
    const int rowbase = (b << 4) + n0;
    #pragma unroll
    for (int j = 0; j < kJ; ++j) {
        const float* Bp = Bm + (size_t)(rowbase + j) * kL + l0;
        const float* Cp = Cm + (size_t)(rowbase + j) * kL + l0;
        float4 b4 = *(const float4*)Bp;
        float4 c4 = *(const float4*)Cp;
        float Bv[4] = {b4.x, b4.y, b4.z, b4.w};
        float Cv[4] = {c4.x, c4.y, c4.z, c4.w};
        float x = 0.f, p = 1.f;
        #pragma unroll
        for (int s = 0; s < kE; ++s) {
            float e = __builtin_amdgcn_exp2f(dt2[s] * aj[j]);
            x = fmaf(e, x, dtu[s] * Bv[s]);
            p *= e;
            Q[j][s] = p * Cv[s];
            y[s] = fmaf(x, Cv[s], y[s]);
        }
        sax[n0 + j][chunk] = make_float2(p, x);
    }
    __syncthreads();   // B1

    // ---- Scanner: wave w owns chunks [32w, 32w+32) ----
    {
        const int sn = lane & 15;            // state n
        const int q  = lane >> 4;            // sub-group (8 chunks)
        const int cb = (wave << 5) + (q << 3);

        float p = 1.f, c = 0.f;
        #pragma unroll
        for (int i = 0; i < 8; ++i) {
            float2 ax = sax[sn][cb + i];
            c = fmaf(ax.x, c, ax.y);
            p *= ax.x;
        }
        float Aq = p, Xq = c;
        {   // inclusive scan over the 4 sub-groups (strides 16, 32)
            float ain = __shfl_up(Aq, 16, 64);
            float xin = __shfl_up(Xq, 16, 64);
            bool act = (lane >= 16);
            Xq = fmaf(Aq, act ? xin : 0.f, Xq);
            Aq *= act ? ain : 1.f;
            ain = __shfl_up(Aq, 32, 64);
            xin = __shfl_up(Xq, 32, 64);
            act = (lane >= 32);
            Xq = fmaf(Aq, act ? xin : 0.f, Xq);
            Aq *= act ? ain : 1.f;
        }
        if (q == 3) sw[wave][sn] = make_float2(Aq, Xq);
        float eA = __shfl_up(Aq, 16, 64);
        float eX = __shfl_up(Xq, 16, 64);
        if (lane < 16) { eA = 1.f; eX = 0.f; }
        __syncthreads();   // B2

        float wx = 0.f;    // prefix over earlier waves
        #pragma unroll
        for (int w = 0; w < 7; ++w) {
            if (w < wave) {
                float2 s2 = sw[w][sn];
                wx = fmaf(s2.x, wx, s2.y);
            }
        }
        float cc = fmaf(eA, wx, eX);
        #pragma unroll
        for (int i = 0; i < 8; ++i) {
            float2 ax = sax[sn][cb + i];
            sax[sn][cb + i].x = cc;
            cc = fmaf(ax.x, cc, ax.y);
        }
    }
    __syncthreads();   // B3

    // ---- Phase 2: y += carry_j * Q_j ----
    #pragma unroll
    for (int j = 0; j < kJ; ++j) {
        float carry = sax[n0 + j][chunk].x;
        #pragma unroll
        for (int s = 0; s < kE; ++s)
            y[s] = fmaf(carry, Q[j][s], y[s]);
    }

    // ---- Split epilogue: each half publishes what the other needs ----
    if (nh == 0) syr[0][chunk] = make_float2(y[2], y[3]);
    else         syr[1][chunk] = make_float2(y[0], y[1]);
    __syncthreads();   // B4

    float2 oth = syr[nh ^ 1][chunk];
    float ya = (nh ? y[2] : y[0]) + oth.x;
    float yb = (nh ? y[3] : y[1]) + oth.y;

    const float D_d = rfl(Dv[d]);
    float s0 = __builtin_amdgcn_rcpf(1.f + __builtin_amdgcn_exp2f(-zv2.x * LOG2E));
    float s1 = __builtin_amdgcn_rcpf(1.f + __builtin_amdgcn_exp2f(-zv2.y * LOG2E));
    float2 o;
    o.x = (ya + ue0 * D_d) * zv2.x * s0;
    o.y = (yb + ue1 * D_d) * zv2.y * s1;
    *(float2*)(out + base + l0 + 2 * nh) = o;
}

}  // namespace

extern "C" void kernel_launch(void* const* d_in, const int* in_sizes, int n_in,
                              void* d_out, int out_size, void* d_ws, size_t ws_size,
                              hipStream_t stream) {
    const float* u     = (const float*)d_in[0];
    const float* delta = (const float*)d_in[1];
    const float* A     = (const float*)d_in[2];
    const float* Bm    = (const float*)d_in[3];
    const float* Cm    = (const float*)d_in[4];
    const float* Dv    = (const float*)d_in[5];
    const float* z     = (const float*)d_in[6];
    float* out = (float*)d_out;

    dim3 grid(2 * kD);
    dim3 block(kT);
    hipLaunchKernelGGL(selscan, grid, block, 0, stream,
                       u, delta, A, Bm, Cm, Dv, z, out);
}

// Round 17
// 22.006 us; speedup vs baseline: 1.4307x; 1.4307x over previous
//
#include <hip/hip_runtime.h>
#include <math.h>

namespace {

constexpr int kD = 1024;
constexpr int kL = 1024;
constexpr int kN = 16;
constexpr int kE = 4;     // l-steps per thread
constexpr int kJ = 8;     // n-states per thread (one nh half)
constexpr int kT = 512;   // threads per block; block = one (b,d)
constexpr int kC = 256;   // l-chunks per (b,d)
constexpr int kCP = kC + 1;

// wave-uniform float -> SGPR
__device__ __forceinline__ float rfl(float x) {
    return __uint_as_float(__builtin_amdgcn_readfirstlane(__float_as_uint(x)));
}

__global__ __launch_bounds__(kT)
void selscan(const float* __restrict__ u,
             const float* __restrict__ delta,
             const float* __restrict__ A,
             const float* __restrict__ Bm,
             const float* __restrict__ Cm,
             const float* __restrict__ Dv,
             const float* __restrict__ z,
             float* __restrict__ out)
{
    __shared__ float2 sax[kN][kCP];  // [n][chunk] (a,x); .x -> carry after scan
    __shared__ float2 sw[8][kN];     // per-wave 32-chunk totals
    __shared__ float2 syr[kC][3];    // upper-half y partials

    const int bd   = blockIdx.x;
    const int b    = bd >> 10;          // kD = 1024
    const int d    = bd & (kD - 1);
    const int t    = threadIdx.x;
    const int lane = t & 63;
    const int wave = t >> 6;
    const int nh   = wave >> 2;         // waves 0-3: n 0-7; waves 4-7: n 8-15
    const int n0   = nh << 3;
    const int chunk = ((wave & 3) << 6) | lane;   // 0..255
    const int l0   = chunk << 2;
    const size_t base = (size_t)bd * kL;

    const float LOG2E = 1.4426950408889634f;
    const float LN2   = 0.6931471805599453f;

    // ---- softplus: dt2 = dt*log2e (exponent form), dtu = dt*u ----
    float dt2[kE], dtu[kE];
    {
        float4 dv = *(const float4*)(delta + base + l0);
        float4 uv = *(const float4*)(u + base + l0);
        float dd[4] = {dv.x, dv.y, dv.z, dv.w};
        float uu[4] = {uv.x, uv.y, uv.z, uv.w};
        #pragma unroll
        for (int s = 0; s < kE; ++s) {
            float x = dd[s];
            float e = __builtin_amdgcn_exp2f(-fabsf(x) * LOG2E);
            float sp = fmaxf(x, 0.f) + __builtin_amdgcn_logf(1.f + e) * LN2;
            dt2[s] = sp * LOG2E;
            dtu[s] = sp * uu[s];
        }
    }

    // ---- A row for this wave's n-half -> SGPRs (wave-uniform) ----
    float aj[kJ];
    {
        const float* Ap = A + d * kN + n0;
        #pragma unroll
        for (int j = 0; j < kJ; ++j) aj[j] = rfl(Ap[j]);
    }

    // ---- Phase 1: local 4-step scan; y_local; Q = P*C; summaries ----
    float Q[kJ][kE];
    float y[kE] = {0.f, 0.f, 0.f, 0.f};
    const int rowbase = (b << 4) + n0;
    #pragma unroll
    for (int j = 0; j < kJ; ++j) {
        const float* Bp = Bm + (size_t)(rowbase + j) * kL + l0;
        const float* Cp = Cm + (size_t)(rowbase + j) * kL + l0;
        float4 b4 = *(const float4*)Bp;
        float4 c4 = *(const float4*)Cp;
        float Bv[4] = {b4.x, b4.y, b4.z, b4.w};
        float Cv[4] = {c4.x, c4.y, c4.z, c4.w};
        float x = 0.f, p = 1.f;
        #pragma unroll
        for (int s = 0; s < kE; ++s) {
            float e = __builtin_amdgcn_exp2f(dt2[s] * aj[j]);
            x = fmaf(e, x, dtu[s] * Bv[s]);
            p *= e;
            Q[j][s] = p * Cv[s];
            y[s] = fmaf(x, Cv[s], y[s]);
        }
        sax[n0 + j][chunk] = make_float2(p, x);
    }
    __syncthreads();   // B1

    // ---- Scanner: wave w owns chunks [32w, 32w+32) ----
    {
        const int sn = lane & 15;            // state n
        const int q  = lane >> 4;            // sub-group (8 chunks)
        const int cb = (wave << 5) + (q << 3);

        float p = 1.f, c = 0.f;
        #pragma unroll
        for (int i = 0; i < 8; ++i) {
            float2 ax = sax[sn][cb + i];
            c = fmaf(ax.x, c, ax.y);
            p *= ax.x;
        }
        float Aq = p, Xq = c;
        {   // inclusive scan over the 4 sub-groups (strides 16, 32)
            float ain = __shfl_up(Aq, 16, 64);
            float xin = __shfl_up(Xq, 16, 64);
            bool act = (lane >= 16);
            Xq = fmaf(Aq, act ? xin : 0.f, Xq);
            Aq *= act ? ain : 1.f;
            ain = __shfl_up(Aq, 32, 64);
            xin = __shfl_up(Xq, 32, 64);
            act = (lane >= 32);
            Xq = fmaf(Aq, act ? xin : 0.f, Xq);
            Aq *= act ? ain : 1.f;
        }
        if (q == 3) sw[wave][sn] = make_float2(Aq, Xq);
        float eA = __shfl_up(Aq, 16, 64);
        float eX = __shfl_up(Xq, 16, 64);
        if (lane < 16) { eA = 1.f; eX = 0.f; }
        __syncthreads();   // B2

        float wx = 0.f;    // prefix over earlier waves
        #pragma unroll
        for (int w = 0; w < 7; ++w) {
            if (w < wave) {
                float2 s2 = sw[w][sn];
                wx = fmaf(s2.x, wx, s2.y);
            }
        }
        float cc = fmaf(eA, wx, eX);
        #pragma unroll
        for (int i = 0; i < 8; ++i) {
            float2 ax = sax[sn][cb + i];
            sax[sn][cb + i].x = cc;
            cc = fmaf(ax.x, cc, ax.y);
        }
    }
    __syncthreads();   // B3

    // ---- Phase 2: y += carry_j * Q_j ----
    #pragma unroll
    for (int j = 0; j < kJ; ++j) {
        float carry = sax[n0 + j][chunk].x;
        #pragma unroll
        for (int s = 0; s < kE; ++s)
            y[s] = fmaf(carry, Q[j][s], y[s]);
    }

    // ---- Cross-wave n-half reduce: upper waves publish y ----
    if (nh == 1) {
        syr[chunk][0] = make_float2(y[0], y[1]);
        syr[chunk][1] = make_float2(y[2], y[3]);
    }
    __syncthreads();   // B4

    // ---- Epilogue (lower waves): combine halves, silu, store ----
    if (nh == 0) {
        float2 ya = syr[chunk][0];
        float2 yb = syr[chunk][1];
        float y0 = y[0] + ya.x;
        float y1 = y[1] + ya.y;
        float y2 = y[2] + yb.x;
        float y3 = y[3] + yb.y;

        const float D_d = rfl(Dv[d]);
        float4 uv = *(const float4*)(u + base + l0);
        float4 zv = *(const float4*)(z + base + l0);
        float s0 = __builtin_amdgcn_rcpf(1.f + __builtin_amdgcn_exp2f(-zv.x * LOG2E));
        float s1 = __builtin_amdgcn_rcpf(1.f + __builtin_amdgcn_exp2f(-zv.y * LOG2E));
        float s2 = __builtin_amdgcn_rcpf(1.f + __builtin_amdgcn_exp2f(-zv.z * LOG2E));
        float s3 = __builtin_amdgcn_rcpf(1.f + __builtin_amdgcn_exp2f(-zv.w * LOG2E));
        float4 o;
        o.x = (y0 + uv.x * D_d) * zv.x * s0;
        o.y = (y1 + uv.y * D_d) * zv.y * s1;
        o.z = (y2 + uv.z * D_d) * zv.z * s2;
        o.w = (y3 + uv.w * D_d) * zv.w * s3;
        *(float4*)(out + base + l0) = o;
    }
}

}  // namespace

extern "C" void kernel_launch(void* const* d_in, const int* in_sizes, int n_in,
                              void* d_out, int out_size, void* d_ws, size_t ws_size,
                              hipStream_t stream) {
    const float* u     = (const float*)d_in[0];
    const float* delta = (const float*)d_in[1];
    const float* A     = (const float*)d_in[2];
    const float* Bm    = (const float*)d_in[3];
    const float* Cm    = (const float*)d_in[4];
    const float* Dv    = (const float*)d_in[5];
    const float* z     = (const float*)d_in[6];
    float* out = (float*)d_out;

    dim3 grid(2 * kD);
    dim3 block(kT);
    hipLaunchKernelGGL(selscan, grid, block, 0, stream,
                       u, delta, A, Bm, Cm, Dv, z, out);
}